// Round 2
// baseline (2866.511 us; speedup 1.0000x reference)
//
#include <hip/hip_runtime.h>
#include <math.h>

typedef unsigned short u16;
typedef unsigned int u32;
typedef __attribute__((ext_vector_type(8))) short short8;
typedef __attribute__((ext_vector_type(4))) float f32x4;
typedef __attribute__((ext_vector_type(4))) u32 u32x4;
typedef __attribute__((ext_vector_type(4))) u16 u16x4;

#define BSZ 8
#define SEQ 1024
#define DIM 1024
#define DFF 4096
#define MROWS (BSZ * SEQ)
#define HOPS 6

__device__ __forceinline__ u16 bf16_rne(float f) {
  u32 u = __float_as_uint(f);
  u32 r = (u + 0x7FFFu + ((u >> 16) & 1u)) >> 16;
  return (u16)r;
}
__device__ __forceinline__ float bf16_to_f(u16 h) {
  return __uint_as_float(((u32)h) << 16);
}

// ---------------------------------------------------------------------------
// Transpose + split: W [K][N] f32  ->  Th/Tl [N][K] bf16 hi/lo planes
// ---------------------------------------------------------------------------
__global__ __launch_bounds__(256)
void tsplit(const float* __restrict__ W, u16* __restrict__ Th, u16* __restrict__ Tl,
            int K, int N) {
  __shared__ float tile[32][33];
  const int n0 = blockIdx.x * 32, k0 = blockIdx.y * 32;
  const int tx = threadIdx.x & 31, ty = threadIdx.x >> 5;  // ty 0..7
#pragma unroll
  for (int i = 0; i < 4; ++i)
    tile[ty + 8 * i][tx] = W[(long)(k0 + ty + 8 * i) * N + n0 + tx];
  __syncthreads();
#pragma unroll
  for (int i = 0; i < 4; ++i) {
    float v = tile[tx][ty + 8 * i];
    long idx = (long)(n0 + ty + 8 * i) * K + k0 + tx;
    u16 h = bf16_rne(v);
    Th[idx] = h;
    Tl[idx] = bf16_rne(v - bf16_to_f(h));
  }
}

// ---------------------------------------------------------------------------
// Per-hop: s = state + ts + ps[step]; split-store s; z = s . w_p; ACT update
// One block (256 thr) per row (b,t).
// ---------------------------------------------------------------------------
__global__ __launch_bounds__(256)
void s_act(const float* __restrict__ state, const float* __restrict__ ts,
           const float* __restrict__ ps, const float* __restrict__ wp,
           const float* __restrict__ bp,
           u16* __restrict__ sh, u16* __restrict__ sl,
           float* __restrict__ uwp, float* __restrict__ hp,
           float* __restrict__ rem, float* __restrict__ nu) {
  const int row = blockIdx.x;
  const int t = row & (SEQ - 1);
  const int tid = threadIdx.x;
  const long gbase = (long)row * DIM + tid * 4;
  const int dbase = tid * 4;
  f32x4 sv = *(const f32x4*)(state + gbase);
  f32x4 tv = *(const f32x4*)(ts + (long)t * DIM + dbase);
  f32x4 pv = *(const f32x4*)(ps + dbase);
  f32x4 wv = *(const f32x4*)(wp + dbase);
  float dot = 0.f;
  u16x4 hh, llv;
#pragma unroll
  for (int i = 0; i < 4; ++i) {
    float s = sv[i] + tv[i] + pv[i];  // matches ref order: (state+ts)+ps
    dot += s * wv[i];
    u16 h = bf16_rne(s);
    hh[i] = h;
    llv[i] = bf16_rne(s - bf16_to_f(h));
  }
  *(u16x4*)(sh + gbase) = hh;
  *(u16x4*)(sl + gbase) = llv;
#pragma unroll
  for (int o = 32; o > 0; o >>= 1) dot += __shfl_down(dot, o);
  __shared__ float red[4];
  if ((tid & 63) == 0) red[tid >> 6] = dot;
  __syncthreads();
  if (tid == 0) {
    float z = red[0] + red[1] + red[2] + red[3] + bp[0];
    float p = 1.0f / (1.0f + expf(-z));
    float h = hp[row], r = rem[row], n = nu[row];
    float sr  = (h < 1.0f) ? 1.0f : 0.0f;
    float a   = h + p * sr;
    float nh  = (a > 0.9f) ? sr : 0.0f;
    float sr2 = (a <= 0.9f) ? sr : 0.0f;
    h = h + p * sr2;            // hp after still-running update
    r = r + nh * (1.0f - h);    // remainders
    h = h + nh * r;             // hp -> exactly 1 at halt
    n = n + sr2 + nh;           // n_updates
    hp[row] = h; rem[row] = r; nu[row] = n;
    uwp[row] = p * sr2 + nh * r;
  }
}

// ---------------------------------------------------------------------------
// Split-precision GEMM: C = A * B^T with A ~ Ah+Al [M][K], B ~ Bh+Bl [N][K]
// 3-term: Ah*Bh + Ah*Bl + Al*Bh  (error ~2^-18 relative)
// MODE 0: hidden = relu(C + bias) -> split-store to Ch/Cl [M][N]
// MODE 1: v = C + bias; prev = v*uw + prev*(1-uw); state = v
// 128x128 block tile, BK=32, 4 waves of 64x64, mfma_f32_16x16x32_bf16
// ---------------------------------------------------------------------------
template <int MODE>
__global__ __launch_bounds__(256, 2)
void gemm3(const u16* __restrict__ Ah, const u16* __restrict__ Al,
           const u16* __restrict__ Bh, const u16* __restrict__ Bl,
           const float* __restrict__ bias,
           int M, int N, int K,
           u16* __restrict__ Ch, u16* __restrict__ Cl,
           const float* __restrict__ uw, float* __restrict__ prev,
           float* __restrict__ state) {
  __shared__ __align__(16) u16 lds[4][4096];  // Ah,Al,Bh,Bl tiles [128][32]
  const int tid = threadIdx.x;
  const int lane = tid & 63;
  const int wave = tid >> 6;
  const int wm = wave >> 1, wn = wave & 1;
  const int m0 = blockIdx.y * 128;
  const int n0 = blockIdx.x * 128;

  // staging: per plane, thread covers rows {g*64 + wave*16 + (lane>>2)}, 16B chunk (lane&3)
  const int srow = wave * 16 + (lane >> 2);
  const int schunk = lane & 3;
  const u16* gp[4];
  gp[0] = Ah + (long)(m0 + srow) * K + schunk * 8;
  gp[1] = Al + (long)(m0 + srow) * K + schunk * 8;
  gp[2] = Bh + (long)(n0 + srow) * K + schunk * 8;
  gp[3] = Bl + (long)(n0 + srow) * K + schunk * 8;
  const int ldsoff = srow * 32 + schunk * 8;

  // fragment addressing
  const int fr = lane & 15, kg = lane >> 4;
  const int aoff = (wm * 64 + fr) * 32 + kg * 8;
  const int boff = (wn * 64 + fr) * 32 + kg * 8;

  const f32x4 fzero = {0.f, 0.f, 0.f, 0.f};
  f32x4 acc[4][4];
#pragma unroll
  for (int m = 0; m < 4; ++m)
#pragma unroll
    for (int n = 0; n < 4; ++n) acc[m][n] = fzero;

  u32x4 sreg[4][2];
#pragma unroll
  for (int pl = 0; pl < 4; ++pl)
#pragma unroll
    for (int g = 0; g < 2; ++g)
      sreg[pl][g] = *(const u32x4*)(gp[pl] + (long)g * 64 * K);

  for (int k0 = 0; k0 < K; k0 += 32) {
    __syncthreads();
#pragma unroll
    for (int pl = 0; pl < 4; ++pl)
#pragma unroll
      for (int g = 0; g < 2; ++g)
        *(u32x4*)&lds[pl][ldsoff + g * 2048] = sreg[pl][g];
    __syncthreads();
    if (k0 + 32 < K) {  // prefetch next K-tile into regs, overlaps with MFMAs
#pragma unroll
      for (int pl = 0; pl < 4; ++pl)
#pragma unroll
        for (int g = 0; g < 2; ++g)
          sreg[pl][g] = *(const u32x4*)(gp[pl] + (long)g * 64 * K + (k0 + 32));
    }
    short8 ahf[4], alf[4], bhf[4], blf[4];
#pragma unroll
    for (int m = 0; m < 4; ++m) {
      ahf[m] = *(const short8*)&lds[0][aoff + m * 512];
      alf[m] = *(const short8*)&lds[1][aoff + m * 512];
    }
#pragma unroll
    for (int n = 0; n < 4; ++n) {
      bhf[n] = *(const short8*)&lds[2][boff + n * 512];
      blf[n] = *(const short8*)&lds[3][boff + n * 512];
    }
#pragma unroll
    for (int m = 0; m < 4; ++m)
#pragma unroll
      for (int n = 0; n < 4; ++n) {
        acc[m][n] = __builtin_amdgcn_mfma_f32_16x16x32_bf16(ahf[m], bhf[n], acc[m][n], 0, 0, 0);
        acc[m][n] = __builtin_amdgcn_mfma_f32_16x16x32_bf16(ahf[m], blf[n], acc[m][n], 0, 0, 0);
        acc[m][n] = __builtin_amdgcn_mfma_f32_16x16x32_bf16(alf[m], bhf[n], acc[m][n], 0, 0, 0);
      }
  }

  // epilogue; C layout: col = lane&15, row = (lane>>4)*4 + i  [m89-verified]
  const int orow0 = m0 + wm * 64 + kg * 4;
  const int ocol0 = n0 + wn * 64 + fr;
#pragma unroll
  for (int n = 0; n < 4; ++n) {
    const int col = ocol0 + n * 16;
    const float bv = bias[col];
#pragma unroll
    for (int m = 0; m < 4; ++m) {
#pragma unroll
      for (int i = 0; i < 4; ++i) {
        const int row = orow0 + m * 16 + i;
        float v = acc[m][n][i] + bv;
        const long idx = (long)row * N + col;
        if constexpr (MODE == 0) {
          v = fmaxf(v, 0.0f);
          u16 h = bf16_rne(v);
          Ch[idx] = h;
          Cl[idx] = bf16_rne(v - bf16_to_f(h));
        } else {
          const float u = uw[row];
          const float pvv = prev[idx];
          prev[idx] = v * u + pvv * (1.0f - u);
          state[idx] = v;
        }
      }
    }
  }
}

// ---------------------------------------------------------------------------
extern "C" void kernel_launch(void* const* d_in, const int* in_sizes, int n_in,
                              void* d_out, int out_size, void* d_ws, size_t ws_size,
                              hipStream_t stream) {
  (void)in_sizes; (void)n_in;
  float* state     = (float*)d_in[0];        // mutated; harness restores each launch
  const float* ts  = (const float*)d_in[1];
  const float* ps  = (const float*)d_in[2];
  const float* wp  = (const float*)d_in[3];
  const float* bp  = (const float*)d_in[4];
  const float* W1  = (const float*)d_in[5];
  const float* b1  = (const float*)d_in[6];
  const float* W2  = (const float*)d_in[7];
  const float* b2  = (const float*)d_in[8];

  float* prev = (float*)d_out;
  float* rem  = prev + (size_t)MROWS * DIM;
  float* nu   = rem + MROWS;

  char* base = (char*)d_ws;
  size_t off = 0;
  auto carve = [&](size_t bytes) -> void* {
    void* p = base + off;
    off += (bytes + 255) & ~(size_t)255;
    return p;
  };
  u16* w1h = (u16*)carve((size_t)DFF * DIM * 2);
  u16* w1l = (u16*)carve((size_t)DFF * DIM * 2);
  u16* w2h = (u16*)carve((size_t)DIM * DFF * 2);
  u16* w2l = (u16*)carve((size_t)DIM * DFF * 2);
  u16* sh  = (u16*)carve((size_t)MROWS * DIM * 2);
  u16* sl  = (u16*)carve((size_t)MROWS * DIM * 2);
  float* uwp = (float*)carve((size_t)MROWS * 4);
  float* hp  = (float*)carve((size_t)MROWS * 4);
  const size_t fixed = off;
  int Ms = MROWS;  // hidden-slice rows; shrink if workspace is small
  while (Ms > 128 && fixed + (size_t)Ms * DFF * 4 > ws_size) Ms >>= 1;
  u16* hidh = (u16*)carve((size_t)Ms * DFF * 2);
  u16* hidl = (u16*)carve((size_t)Ms * DFF * 2);

  hipMemsetAsync(d_out, 0, (size_t)out_size * 4, stream);  // prev/rem/nu = 0
  hipMemsetAsync(hp, 0, (size_t)MROWS * 4, stream);

  // once per launch: W1 -> [DFF][DIM] planes, W2 -> [DIM][DFF] planes
  tsplit<<<dim3(DFF / 32, DIM / 32), 256, 0, stream>>>(W1, w1h, w1l, DIM, DFF);
  tsplit<<<dim3(DIM / 32, DFF / 32), 256, 0, stream>>>(W2, w2h, w2l, DFF, DIM);

  for (int step = 0; step < HOPS; ++step) {
    s_act<<<MROWS, 256, 0, stream>>>(state, ts, ps + (size_t)step * DIM, wp, bp,
                                     sh, sl, uwp, hp, rem, nu);
    for (int r0 = 0; r0 < MROWS; r0 += Ms) {
      gemm3<0><<<dim3(DFF / 128, Ms / 128), 256, 0, stream>>>(
          sh + (size_t)r0 * DIM, sl + (size_t)r0 * DIM, w1h, w1l, b1,
          Ms, DFF, DIM, hidh, hidl, nullptr, nullptr, nullptr);
      gemm3<1><<<dim3(DIM / 128, Ms / 128), 256, 0, stream>>>(
          hidh, hidl, w2h, w2l, b2,
          Ms, DIM, DFF, nullptr, nullptr,
          uwp + r0, prev + (size_t)r0 * DIM, state + (size_t)r0 * DIM);
    }
  }
}

// Round 4
// 2641.096 us; speedup vs baseline: 1.0853x; 1.0853x over previous
//
#include <hip/hip_runtime.h>
#include <math.h>

typedef unsigned short u16;
typedef unsigned int u32;
typedef __attribute__((ext_vector_type(8))) short short8;
typedef __attribute__((ext_vector_type(4))) float f32x4;
typedef __attribute__((ext_vector_type(4))) u16 u16x4;

#define BSZ 8
#define SEQ 1024
#define DIM 1024
#define DFF 4096
#define MROWS (BSZ * SEQ)
#define HOPS 6

typedef __attribute__((address_space(3))) u32 as3_u32;
typedef __attribute__((address_space(1))) const u32 as1_u32;
#define GLDS(g, l) __builtin_amdgcn_global_load_lds((as1_u32*)(g), (as3_u32*)(l), 16, 0, 0)

__device__ __forceinline__ u16 bf16_rne(float f) {
  u32 u = __float_as_uint(f);
  u32 r = (u + 0x7FFFu + ((u >> 16) & 1u)) >> 16;
  return (u16)r;
}
__device__ __forceinline__ float bf16_to_f(u16 h) {
  return __uint_as_float(((u32)h) << 16);
}

// ---------------------------------------------------------------------------
// Transpose + split: W [K][N] f32 -> Th/Tl [N][K] bf16 hi/lo planes
// ---------------------------------------------------------------------------
__global__ __launch_bounds__(256)
void tsplit(const float* __restrict__ W, u16* __restrict__ Th, u16* __restrict__ Tl,
            int K, int N) {
  __shared__ float tile[32][33];
  const int n0 = blockIdx.x * 32, k0 = blockIdx.y * 32;
  const int tx = threadIdx.x & 31, ty = threadIdx.x >> 5;
#pragma unroll
  for (int i = 0; i < 4; ++i)
    tile[ty + 8 * i][tx] = W[(long)(k0 + ty + 8 * i) * N + n0 + tx];
  __syncthreads();
#pragma unroll
  for (int i = 0; i < 4; ++i) {
    float v = tile[tx][ty + 8 * i];
    long idx = (long)(n0 + ty + 8 * i) * K + k0 + tx;
    u16 h = bf16_rne(v);
    Th[idx] = h;
    Tl[idx] = bf16_rne(v - bf16_to_f(h));
  }
}

// ---------------------------------------------------------------------------
// Per-hop: s = state + ts + ps[step]; split-store s; z = s . w_p; ACT update
// ---------------------------------------------------------------------------
__global__ __launch_bounds__(256)
void s_act(const float* __restrict__ state, const float* __restrict__ ts,
           const float* __restrict__ ps, const float* __restrict__ wp,
           const float* __restrict__ bp,
           u16* __restrict__ sh, u16* __restrict__ sl,
           float* __restrict__ uwp, float* __restrict__ hp,
           float* __restrict__ rem, float* __restrict__ nu) {
  const int row = blockIdx.x;
  const int t = row & (SEQ - 1);
  const int tid = threadIdx.x;
  const long gbase = (long)row * DIM + tid * 4;
  const int dbase = tid * 4;
  f32x4 sv = *(const f32x4*)(state + gbase);
  f32x4 tv = *(const f32x4*)(ts + (long)t * DIM + dbase);
  f32x4 pv = *(const f32x4*)(ps + dbase);
  f32x4 wv = *(const f32x4*)(wp + dbase);
  float dot = 0.f;
  u16x4 hh, llv;
#pragma unroll
  for (int i = 0; i < 4; ++i) {
    float s = sv[i] + tv[i] + pv[i];
    dot += s * wv[i];
    u16 h = bf16_rne(s);
    hh[i] = h;
    llv[i] = bf16_rne(s - bf16_to_f(h));
  }
  *(u16x4*)(sh + gbase) = hh;
  *(u16x4*)(sl + gbase) = llv;
#pragma unroll
  for (int o = 32; o > 0; o >>= 1) dot += __shfl_down(dot, o);
  __shared__ float red[4];
  if ((tid & 63) == 0) red[tid >> 6] = dot;
  __syncthreads();
  if (tid == 0) {
    float z = red[0] + red[1] + red[2] + red[3] + bp[0];
    float p = 1.0f / (1.0f + expf(-z));
    float h = hp[row], r = rem[row], n = nu[row];
    float sr  = (h < 1.0f) ? 1.0f : 0.0f;
    float a   = h + p * sr;
    float nh  = (a > 0.9f) ? sr : 0.0f;
    float sr2 = (a <= 0.9f) ? sr : 0.0f;
    h = h + p * sr2;
    r = r + nh * (1.0f - h);
    h = h + nh * r;
    n = n + sr2 + nh;
    hp[row] = h; rem[row] = r; nu[row] = n;
    uwp[row] = p * sr2 + nh * r;
  }
}

// ---------------------------------------------------------------------------
// 8-phase 256x256 BK=64 split-f32 GEMM (K' = 3K).
// Tile c = T%3 selects planes: A {h,h,l}, B {h,l,h}
//   -> terms Ah.Bh + Ah.Bl + Al.Bh  (round-3 bug: was (c==1) on BOTH -> 2*AhBh+AlBl)
// C = A'.B'^T, A planes [M][ldK], B planes [N][ldK]. 8 waves (2Mx4N), per-wave
// C 128x64. LDS 128KB: 2 bufs x (A 32KB + B 32KB), halves of 16KB.
// XOR slot-swizzle: phys_slot = logical_slot ^ (row&7) (pre-swizzled gload src).
// MODE 0: out = relu(C+bias) split-stored to outH/outL [M][NCOLS]
// MODE 1: parts[bz][M][NCOLS] = C (split-K partial, bias added in combine)
// ---------------------------------------------------------------------------
template <int MODE, int NCOLS>
__global__ __launch_bounds__(512, 2)
void gemm8(const u16* __restrict__ aH, const u16* __restrict__ aL,
           const u16* __restrict__ bH, const u16* __restrict__ bL,
           int ldK, int ntPerSplit,
           const float* __restrict__ bias,
           u16* __restrict__ outH, u16* __restrict__ outL,
           float* __restrict__ parts, int Mrows) {
  __shared__ __align__(16) char lds[131072];
  const int tid = threadIdx.x, lane = tid & 63, wave = tid >> 6;
  const int wm = wave >> 2, wn = wave & 3;

  // XCD-aware swizzle over flattened grid (nwg % 8 == 0 by construction)
  const int gx = gridDim.x, gy = gridDim.y;
  const int nwg = gx * gy * gridDim.z;
  int id = (blockIdx.z * gy + blockIdx.y) * gx + blockIdx.x;
  int swz = (id & 7) * (nwg >> 3) + (id >> 3);
  const int bx = swz % gx;
  int t1 = swz / gx;
  const int by = t1 % gy, bz = t1 / gy;
  const int m0 = by * 256, n0 = bx * 256;
  const int tile0 = bz * ntPerSplit;   // even, multiple of 3 (ntPerSplit % 6 == 0)
  const int NT = ntPerSplit;
  const int niter = NT >> 1;

  // ---- staging precompute (pre-swizzled global source offsets, bytes)
  const int l8 = lane >> 3, l7 = lane & 7;
  const int lslot = l7 ^ l8;
  u32 rA[2][2], rB[2][2];
#pragma unroll
  for (int hf = 0; hf < 2; ++hf)
#pragma unroll
    for (int g = 0; g < 2; ++g) {
      rA[hf][g] = (u32)(((m0 + hf * 128 + g * 64 + wave * 8 + l8) * ldK + lslot * 8) * 2);
      rB[hf][g] = (u32)(((n0 + hf * 128 + g * 64 + wave * 8 + l8) * ldK + lslot * 8) * 2);
    }

  // stage one half-tile (hf: 0=Aa,1=Ab,2=Ba,3=Bb) of absolute tile T
  auto stage = [&](int T, int hf) {
    const int c = T - (T / 3) * 3;           // 0,1,2 within k-col group
    const int colb = (T / 3) * 128;          // 64 elems * 2B
    const int buf = T & 1;
    char* ldsb = &lds[buf * 65536 + (hf >= 2 ? 32768 : 0) + (hf & 1) * 16384 + wave * 1024];
    const u16* pl;
    u32 r0b, r1b;
    if (hf < 2) { pl = (c == 2) ? aL : aH; r0b = rA[hf][0]; r1b = rA[hf][1]; }      // A: h,h,l
    else        { pl = (c == 1) ? bL : bH; r0b = rB[hf - 2][0]; r1b = rB[hf - 2][1]; } // B: h,l,h
    GLDS((const char*)pl + r0b + colb, ldsb);
    GLDS((const char*)pl + r1b + colb, ldsb + 8192);
  };

  // ---- reader precompute (swizzled ds_read addresses)
  const int fr = lane & 15, kg = lane >> 4;
  const int fb2 = (fr >> 2) & 1;
  const int sks[2] = {fb2 << 6, (fb2 ^ 1) << 6};
  const int laneRC = fr * 128 + ((kg ^ (fr & 3)) << 4);
  const int aBaseH = wm * 16384;
  const int bBaseH = 32768 + (wn >> 1) * 16384 + (wn & 1) * 8192;

  f32x4 acc[8][4];
  const f32x4 fz = {0.f, 0.f, 0.f, 0.f};
#pragma unroll
  for (int m = 0; m < 8; ++m)
#pragma unroll
    for (int n = 0; n < 4; ++n) acc[m][n] = fz;

#define LDS8(off) (*(const short8*)&lds[(off)])

  // prologue: tile0 full + tile1 half Aa; ensure tile0 landed
  stage(tile0 + 0, 0); stage(tile0 + 0, 1); stage(tile0 + 0, 2); stage(tile0 + 0, 3);
  stage(tile0 + 1, 0);
  asm volatile("s_waitcnt vmcnt(2)" ::: "memory");
  __builtin_amdgcn_s_barrier();

  for (int it = 0; it < niter; ++it) {
#pragma unroll
    for (int ht = 0; ht < 2; ++ht) {
      const int buf = ht;  // (tile0 + 2it + ht) & 1 == ht  (tile0 even)
      const int abase = buf * 65536 + aBaseH;
      const int bbase = buf * 65536 + bBaseH;
      short8 aF[4][2], bF[4][2];
#pragma unroll
      for (int ph = 0; ph < 4; ++ph) {
        // --- ds reads for this phase's quadrant
        if (ph == 0) {
#pragma unroll
          for (int mf = 0; mf < 4; ++mf) {
            aF[mf][0] = LDS8(abase + mf * 2048 + laneRC + sks[0]);
            aF[mf][1] = LDS8(abase + mf * 2048 + laneRC + sks[1]);
          }
#pragma unroll
          for (int nf = 0; nf < 2; ++nf) {
            bF[nf][0] = LDS8(bbase + nf * 2048 + laneRC + sks[0]);
            bF[nf][1] = LDS8(bbase + nf * 2048 + laneRC + sks[1]);
          }
        } else if (ph == 1) {
#pragma unroll
          for (int nf = 2; nf < 4; ++nf) {
            bF[nf][0] = LDS8(bbase + nf * 2048 + laneRC + sks[0]);
            bF[nf][1] = LDS8(bbase + nf * 2048 + laneRC + sks[1]);
          }
        } else if (ph == 2) {
#pragma unroll
          for (int mf = 0; mf < 4; ++mf) {
            aF[mf][0] = LDS8(abase + (4 + mf) * 2048 + laneRC + sks[0]);
            aF[mf][1] = LDS8(abase + (4 + mf) * 2048 + laneRC + sks[1]);
          }
        }
        // --- stage one half-tile (gp = 8*it + ht*4 + ph + 1)
        {
          const int gp = 8 * it + ht * 4 + ph + 1;
          const int T = (gp + 4) >> 2;           // local tile index
          const int hf = (ht * 4 + ph + 5) & 3;  // compile-time per phase
          if (T < NT) stage(tile0 + T, hf);
        }
        __builtin_amdgcn_s_barrier();
        asm volatile("s_waitcnt lgkmcnt(0)" ::: "memory");
        __builtin_amdgcn_s_setprio(1);
        {
          const int qm = ph >> 1, qn = ph & 1;
#pragma unroll
          for (int mm = 0; mm < 4; ++mm)
#pragma unroll
            for (int nn = 0; nn < 2; ++nn) {
              const int mf = qm * 4 + mm, nf = qn * 2 + nn;
              acc[mf][nf] = __builtin_amdgcn_mfma_f32_16x16x32_bf16(aF[mm][0], bF[nf][0], acc[mf][nf], 0, 0, 0);
              acc[mf][nf] = __builtin_amdgcn_mfma_f32_16x16x32_bf16(aF[mm][1], bF[nf][1], acc[mf][nf], 0, 0, 0);
            }
        }
        __builtin_amdgcn_s_setprio(0);
        if (ph == 3) {
          if (it + 1 == niter) { asm volatile("s_waitcnt vmcnt(0)" ::: "memory"); }
          else                 { asm volatile("s_waitcnt vmcnt(2)" ::: "memory"); }
        }
        __builtin_amdgcn_s_barrier();
      }
    }
  }

  // ---- epilogue; C layout: col = lane&15, row = (lane>>4)*4 + i
  const int orow = m0 + wm * 128 + kg * 4;
  const int ocol = n0 + wn * 64 + fr;
#pragma unroll
  for (int mf = 0; mf < 8; ++mf)
#pragma unroll
    for (int nf = 0; nf < 4; ++nf) {
      const int col = ocol + nf * 16;
      if constexpr (MODE == 0) {
        const float bv = bias[col];
#pragma unroll
        for (int i2 = 0; i2 < 4; ++i2) {
          const int row = orow + mf * 16 + i2;
          float v = fmaxf(acc[mf][nf][i2] + bv, 0.f);
          const size_t idx = (size_t)row * NCOLS + col;
          u16 h = bf16_rne(v);
          outH[idx] = h;
          outL[idx] = bf16_rne(v - bf16_to_f(h));
        }
      } else {
        float* pp = parts + (size_t)bz * Mrows * NCOLS;
#pragma unroll
        for (int i2 = 0; i2 < 4; ++i2) {
          const int row = orow + mf * 16 + i2;
          pp[(size_t)row * NCOLS + col] = acc[mf][nf][i2];
        }
      }
    }
#undef LDS8
}

// ---------------------------------------------------------------------------
// Split-K combine: v = sum_k parts[k] + b2; prev = v*uw + prev*(1-uw); state = v
// ---------------------------------------------------------------------------
__global__ __launch_bounds__(256)
void combine(const float* __restrict__ parts, long pstride, int nparts,
             const float* __restrict__ b2, const float* __restrict__ uwp,
             float* __restrict__ prev, float* __restrict__ state, int n4) {
  for (int idx = blockIdx.x * blockDim.x + threadIdx.x; idx < n4;
       idx += gridDim.x * blockDim.x) {
    const int row = idx >> 8, c4 = idx & 255;
    f32x4 a = ((const f32x4*)parts)[idx];
    for (int k = 1; k < nparts; ++k) {
      f32x4 b = *(const f32x4*)(parts + (long)k * pstride + (long)idx * 4);
#pragma unroll
      for (int j = 0; j < 4; ++j) a[j] += b[j];
    }
    f32x4 bv = ((const f32x4*)b2)[c4];
    const float u = uwp[row];
    f32x4 pr = ((const f32x4*)prev)[idx];
    f32x4 s, o;
#pragma unroll
    for (int j = 0; j < 4; ++j) {
      s[j] = a[j] + bv[j];
      o[j] = s[j] * u + pr[j] * (1.0f - u);
    }
    ((f32x4*)prev)[idx] = o;
    ((f32x4*)state)[idx] = s;
  }
}

// ---------------------------------------------------------------------------
extern "C" void kernel_launch(void* const* d_in, const int* in_sizes, int n_in,
                              void* d_out, int out_size, void* d_ws, size_t ws_size,
                              hipStream_t stream) {
  (void)in_sizes; (void)n_in;
  float* state     = (float*)d_in[0];  // mutated; harness restores each launch
  const float* ts  = (const float*)d_in[1];
  const float* ps  = (const float*)d_in[2];
  const float* wp  = (const float*)d_in[3];
  const float* bp  = (const float*)d_in[4];
  const float* W1  = (const float*)d_in[5];
  const float* b1  = (const float*)d_in[6];
  const float* W2  = (const float*)d_in[7];
  const float* b2  = (const float*)d_in[8];

  float* prev = (float*)d_out;
  float* rem  = prev + (size_t)MROWS * DIM;
  float* nu   = rem + MROWS;

  char* base = (char*)d_ws;
  size_t off = 0;
  auto carve = [&](size_t bytes) -> void* {
    void* p = base + off;
    off += (bytes + 255) & ~(size_t)255;
    return p;
  };
  u16* w1h = (u16*)carve((size_t)DFF * DIM * 2);
  u16* w1l = (u16*)carve((size_t)DFF * DIM * 2);
  u16* w2h = (u16*)carve((size_t)DIM * DFF * 2);
  u16* w2l = (u16*)carve((size_t)DIM * DFF * 2);
  u16* sh  = (u16*)carve((size_t)MROWS * DIM * 2);
  u16* sl  = (u16*)carve((size_t)MROWS * DIM * 2);
  float* uwp = (float*)carve((size_t)MROWS * 4);
  float* hp  = (float*)carve((size_t)MROWS * 4);
  const size_t fixed = off;
  // parts buffer is a constant 64MB: sk = 16384/Ms partials of [Ms][DIM] f32
  int Ms = MROWS;  // slice rows if workspace is small; hid = 16384 B per row
  while (Ms > 256 && fixed + (size_t)16384 * DIM * 4 + (size_t)Ms * 16384 > ws_size)
    Ms >>= 1;
  u16* hidh    = (u16*)carve((size_t)Ms * DFF * 2);
  u16* hidl    = (u16*)carve((size_t)Ms * DFF * 2);
  float* parts = (float*)carve((size_t)16384 * DIM * 4);
  const int sk = 16384 / Ms;             // 2 for Ms=8192
  const int ntps = 192 / sk;             // multiple of 6: parity + mod-3 alignment

  hipMemsetAsync(d_out, 0, (size_t)out_size * 4, stream);
  hipMemsetAsync(hp, 0, (size_t)MROWS * 4, stream);

  tsplit<<<dim3(DFF / 32, DIM / 32), 256, 0, stream>>>(W1, w1h, w1l, DIM, DFF);
  tsplit<<<dim3(DIM / 32, DFF / 32), 256, 0, stream>>>(W2, w2h, w2l, DFF, DIM);

  for (int step = 0; step < HOPS; ++step) {
    s_act<<<MROWS, 256, 0, stream>>>(state, ts, ps + (size_t)step * DIM, wp, bp,
                                     sh, sl, uwp, hp, rem, nu);
    for (int r0 = 0; r0 < MROWS; r0 += Ms) {
      // GEMM1: [Ms x 1024] x [4096 x 1024]^T, K' = 48 tiles
      gemm8<0, DFF><<<dim3(DFF / 256, Ms / 256, 1), 512, 0, stream>>>(
          sh + (size_t)r0 * DIM, sl + (size_t)r0 * DIM, w1h, w1l,
          DIM, 48, b1, hidh, hidl, nullptr, Ms);
      // GEMM2: [Ms x 4096] x [1024 x 4096]^T, K' = 192 tiles, split-K=sk
      gemm8<1, DIM><<<dim3(DIM / 256, Ms / 256, sk), 512, 0, stream>>>(
          hidh, hidl, w2h, w2l,
          DFF, ntps, nullptr, nullptr, nullptr, parts, Ms);
      combine<<<2048, 256, 0, stream>>>(
          parts, (long)Ms * DIM, sk, b2, uwp + r0,
          prev + (size_t)r0 * DIM, state + (size_t)r0 * DIM, Ms * 256);
    }
  }
}

// Round 5
// 2129.416 us; speedup vs baseline: 1.3461x; 1.2403x over previous
//
#include <hip/hip_runtime.h>
#include <math.h>

typedef unsigned short u16;
typedef unsigned int u32;
typedef __attribute__((ext_vector_type(8))) short short8;
typedef __attribute__((ext_vector_type(4))) float f32x4;
typedef __attribute__((ext_vector_type(4))) u16 u16x4;

#define BSZ 8
#define SEQ 1024
#define DIM 1024
#define DFF 4096
#define MROWS (BSZ * SEQ)
#define HOPS 6

typedef __attribute__((address_space(3))) u32 as3_u32;
typedef __attribute__((address_space(1))) const u32 as1_u32;
#define GLDS(g, l) __builtin_amdgcn_global_load_lds((as1_u32*)(g), (as3_u32*)(l), 16, 0, 0)

__device__ __forceinline__ u16 bf16_rne(float f) {
  u32 u = __float_as_uint(f);
  u32 r = (u + 0x7FFFu + ((u >> 16) & 1u)) >> 16;
  return (u16)r;
}
__device__ __forceinline__ float bf16_to_f(u16 h) {
  return __uint_as_float(((u32)h) << 16);
}
// gate check: 1 = run, 0 = this hop is provably output-neutral -> skip
__device__ __forceinline__ int gchk(const int* g) {
  return g ? __hip_atomic_load(g, __ATOMIC_RELAXED, __HIP_MEMORY_SCOPE_AGENT) : 1;
}

// ---------------------------------------------------------------------------
// Transpose + split: W [K][N] f32 -> Th/Tl [N][K] bf16 hi/lo planes
// ---------------------------------------------------------------------------
__global__ __launch_bounds__(256)
void tsplit(const float* __restrict__ W, u16* __restrict__ Th, u16* __restrict__ Tl,
            int K, int N) {
  __shared__ float tile[32][33];
  const int n0 = blockIdx.x * 32, k0 = blockIdx.y * 32;
  const int tx = threadIdx.x & 31, ty = threadIdx.x >> 5;
#pragma unroll
  for (int i = 0; i < 4; ++i)
    tile[ty + 8 * i][tx] = W[(long)(k0 + ty + 8 * i) * N + n0 + tx];
  __syncthreads();
#pragma unroll
  for (int i = 0; i < 4; ++i) {
    float v = tile[tx][ty + 8 * i];
    long idx = (long)(n0 + ty + 8 * i) * K + k0 + tx;
    u16 h = bf16_rne(v);
    Th[idx] = h;
    Tl[idx] = bf16_rne(v - bf16_to_f(h));
  }
}

// ---------------------------------------------------------------------------
// Per-hop s_act. NP=0: v = src (state array). NP=2: v = parts0+parts1+b2 and
// fused prev-blend with PREVIOUS hop's uw (combine fusion).
// Then: s = v + ts + ps[k]; split-store s; z = s.w_p; ACT update; gate[k] set
// by any still-running row. Early-exit if gateChk (prev hop's gate) is 0.
// ---------------------------------------------------------------------------
template <int NP>
__global__ __launch_bounds__(256)
void s_act_k(const float* __restrict__ src, long pstride,
             const float* __restrict__ b2, float* __restrict__ prevO,
             const float* __restrict__ ts, const float* __restrict__ ps,
             const float* __restrict__ wp, const float* __restrict__ bp,
             u16* __restrict__ sh, u16* __restrict__ sl,
             float* __restrict__ uwp, float* __restrict__ hp,
             float* __restrict__ rem, float* __restrict__ nu,
             int* __restrict__ gate, int k, const int* __restrict__ gateChk) {
  if (!gchk(gateChk)) return;
  const int row = blockIdx.x;
  const int t = row & (SEQ - 1);
  const int tid = threadIdx.x;
  const long gbase = (long)row * DIM + tid * 4;
  const int dbase = tid * 4;
  f32x4 vv;
  if constexpr (NP == 0) {
    vv = *(const f32x4*)(src + gbase);
  } else {
    f32x4 a = *(const f32x4*)(src + gbase);
    f32x4 c = *(const f32x4*)(src + pstride + gbase);
    f32x4 bv = *(const f32x4*)(b2 + dbase);
#pragma unroll
    for (int j = 0; j < 4; ++j) vv[j] = a[j] + c[j] + bv[j];
    // fused combine for hop k-1: prev = v*uw + prev*(1-uw)
    const float u = uwp[row];  // read strictly before tid0's overwrite (barrier below)
    f32x4 pr = *(const f32x4*)(prevO + gbase);
    f32x4 po;
#pragma unroll
    for (int j = 0; j < 4; ++j) po[j] = vv[j] * u + pr[j] * (1.0f - u);
    *(f32x4*)(prevO + gbase) = po;
  }
  f32x4 tv = *(const f32x4*)(ts + (long)t * DIM + dbase);
  f32x4 pv = *(const f32x4*)(ps + dbase);
  f32x4 wv = *(const f32x4*)(wp + dbase);
  float dot = 0.f;
  u16x4 hh, llv;
#pragma unroll
  for (int i = 0; i < 4; ++i) {
    float s = vv[i] + tv[i] + pv[i];
    dot += s * wv[i];
    u16 h = bf16_rne(s);
    hh[i] = h;
    llv[i] = bf16_rne(s - bf16_to_f(h));
  }
  *(u16x4*)(sh + gbase) = hh;
  *(u16x4*)(sl + gbase) = llv;
#pragma unroll
  for (int o = 32; o > 0; o >>= 1) dot += __shfl_down(dot, o);
  __shared__ float red[4];
  if ((tid & 63) == 0) red[tid >> 6] = dot;
  __syncthreads();
  if (tid == 0) {
    float z = red[0] + red[1] + red[2] + red[3] + bp[0];
    float p = 1.0f / (1.0f + expf(-z));
    float h = hp[row], r = rem[row], n = nu[row];
    float sr  = (h < 1.0f) ? 1.0f : 0.0f;
    if (sr > 0.0f)
      __hip_atomic_store(&gate[k], 1, __ATOMIC_RELAXED, __HIP_MEMORY_SCOPE_AGENT);
    float a   = h + p * sr;
    float nh  = (a > 0.9f) ? sr : 0.0f;
    float sr2 = (a <= 0.9f) ? sr : 0.0f;
    h = h + p * sr2;
    r = r + nh * (1.0f - h);
    h = h + nh * r;
    n = n + sr2 + nh;
    hp[row] = h; rem[row] = r; nu[row] = n;
    uwp[row] = p * sr2 + nh * r;
  }
}

// ---------------------------------------------------------------------------
// 8-phase 256x256 BK=64 split-f32 GEMM (K' = 3K).
// Tile c = T%3 selects planes: A {h,h,l}, B {h,l,h} -> AhBh + AlBh + AhBl.
// 8 waves (2Mx4N), per-wave C 128x64. LDS 128KB dbuf. XOR slot-swizzle via
// pre-swizzled global source (gload_lds dest linear) + swizzled ds_read.
// MODE 0: out = relu(C+bias) split-stored. MODE 1: parts[bz] = C.
// Early-exit on gate==0 (hop provably output-neutral).
// ---------------------------------------------------------------------------
template <int MODE, int NCOLS>
__global__ __launch_bounds__(512, 2)
void gemm8(const u16* __restrict__ aH, const u16* __restrict__ aL,
           const u16* __restrict__ bH, const u16* __restrict__ bL,
           int ldK, int ntPerSplit,
           const float* __restrict__ bias,
           u16* __restrict__ outH, u16* __restrict__ outL,
           float* __restrict__ parts, int Mrows, const int* __restrict__ gate) {
  if (!gchk(gate)) return;
  __shared__ __align__(16) char lds[131072];
  const int tid = threadIdx.x, lane = tid & 63, wave = tid >> 6;
  const int wm = wave >> 2, wn = wave & 3;

  const int gx = gridDim.x, gy = gridDim.y;
  const int nwg = gx * gy * gridDim.z;
  int id = (blockIdx.z * gy + blockIdx.y) * gx + blockIdx.x;
  int swz = (id & 7) * (nwg >> 3) + (id >> 3);
  const int bx = swz % gx;
  int t1 = swz / gx;
  const int by = t1 % gy, bz = t1 / gy;
  const int m0 = by * 256, n0 = bx * 256;
  const int tile0 = bz * ntPerSplit;   // even, multiple of 3 (ntPerSplit % 6 == 0)
  const int NT = ntPerSplit;
  const int niter = NT >> 1;

  const int l8 = lane >> 3, l7 = lane & 7;
  const int lslot = l7 ^ l8;
  u32 rA[2][2], rB[2][2];
#pragma unroll
  for (int hf = 0; hf < 2; ++hf)
#pragma unroll
    for (int g = 0; g < 2; ++g) {
      rA[hf][g] = (u32)(((m0 + hf * 128 + g * 64 + wave * 8 + l8) * ldK + lslot * 8) * 2);
      rB[hf][g] = (u32)(((n0 + hf * 128 + g * 64 + wave * 8 + l8) * ldK + lslot * 8) * 2);
    }

  auto stage = [&](int T, int hf) {
    const int c = T - (T / 3) * 3;
    const int colb = (T / 3) * 128;
    const int buf = T & 1;
    char* ldsb = &lds[buf * 65536 + (hf >= 2 ? 32768 : 0) + (hf & 1) * 16384 + wave * 1024];
    const u16* pl;
    u32 r0b, r1b;
    if (hf < 2) { pl = (c == 2) ? aL : aH; r0b = rA[hf][0]; r1b = rA[hf][1]; }      // A: h,h,l
    else        { pl = (c == 1) ? bL : bH; r0b = rB[hf - 2][0]; r1b = rB[hf - 2][1]; } // B: h,l,h
    GLDS((const char*)pl + r0b + colb, ldsb);
    GLDS((const char*)pl + r1b + colb, ldsb + 8192);
  };

  const int fr = lane & 15, kg = lane >> 4;
  const int fb2 = (fr >> 2) & 1;
  const int sks[2] = {fb2 << 6, (fb2 ^ 1) << 6};
  const int laneRC = fr * 128 + ((kg ^ (fr & 3)) << 4);
  const int aBaseH = wm * 16384;
  const int bBaseH = 32768 + (wn >> 1) * 16384 + (wn & 1) * 8192;

  f32x4 acc[8][4];
  const f32x4 fz = {0.f, 0.f, 0.f, 0.f};
#pragma unroll
  for (int m = 0; m < 8; ++m)
#pragma unroll
    for (int n = 0; n < 4; ++n) acc[m][n] = fz;

#define LDS8(off) (*(const short8*)&lds[(off)])

  stage(tile0 + 0, 0); stage(tile0 + 0, 1); stage(tile0 + 0, 2); stage(tile0 + 0, 3);
  stage(tile0 + 1, 0);
  asm volatile("s_waitcnt vmcnt(2)" ::: "memory");
  __builtin_amdgcn_s_barrier();

  for (int it = 0; it < niter; ++it) {
#pragma unroll
    for (int ht = 0; ht < 2; ++ht) {
      const int buf = ht;
      const int abase = buf * 65536 + aBaseH;
      const int bbase = buf * 65536 + bBaseH;
      short8 aF[4][2], bF[4][2];
#pragma unroll
      for (int ph = 0; ph < 4; ++ph) {
        if (ph == 0) {
#pragma unroll
          for (int mf = 0; mf < 4; ++mf) {
            aF[mf][0] = LDS8(abase + mf * 2048 + laneRC + sks[0]);
            aF[mf][1] = LDS8(abase + mf * 2048 + laneRC + sks[1]);
          }
#pragma unroll
          for (int nf = 0; nf < 2; ++nf) {
            bF[nf][0] = LDS8(bbase + nf * 2048 + laneRC + sks[0]);
            bF[nf][1] = LDS8(bbase + nf * 2048 + laneRC + sks[1]);
          }
        } else if (ph == 1) {
#pragma unroll
          for (int nf = 2; nf < 4; ++nf) {
            bF[nf][0] = LDS8(bbase + nf * 2048 + laneRC + sks[0]);
            bF[nf][1] = LDS8(bbase + nf * 2048 + laneRC + sks[1]);
          }
        } else if (ph == 2) {
#pragma unroll
          for (int mf = 0; mf < 4; ++mf) {
            aF[mf][0] = LDS8(abase + (4 + mf) * 2048 + laneRC + sks[0]);
            aF[mf][1] = LDS8(abase + (4 + mf) * 2048 + laneRC + sks[1]);
          }
        }
        {
          const int gp = 8 * it + ht * 4 + ph + 1;
          const int T = (gp + 4) >> 2;
          const int hf = (ht * 4 + ph + 5) & 3;
          if (T < NT) stage(tile0 + T, hf);
        }
        __builtin_amdgcn_s_barrier();
        asm volatile("s_waitcnt lgkmcnt(0)" ::: "memory");
        __builtin_amdgcn_s_setprio(1);
        {
          const int qm = ph >> 1, qn = ph & 1;
#pragma unroll
          for (int mm = 0; mm < 4; ++mm)
#pragma unroll
            for (int nn = 0; nn < 2; ++nn) {
              const int mf = qm * 4 + mm, nf = qn * 2 + nn;
              acc[mf][nf] = __builtin_amdgcn_mfma_f32_16x16x32_bf16(aF[mm][0], bF[nf][0], acc[mf][nf], 0, 0, 0);
              acc[mf][nf] = __builtin_amdgcn_mfma_f32_16x16x32_bf16(aF[mm][1], bF[nf][1], acc[mf][nf], 0, 0, 0);
            }
        }
        __builtin_amdgcn_s_setprio(0);
        if (ph == 3) {
          if (it + 1 == niter) { asm volatile("s_waitcnt vmcnt(0)" ::: "memory"); }
          else                 { asm volatile("s_waitcnt vmcnt(2)" ::: "memory"); }
        }
        __builtin_amdgcn_s_barrier();
      }
    }
  }

  const int orow = m0 + wm * 128 + kg * 4;
  const int ocol = n0 + wn * 64 + fr;
#pragma unroll
  for (int mf = 0; mf < 8; ++mf)
#pragma unroll
    for (int nf = 0; nf < 4; ++nf) {
      const int col = ocol + nf * 16;
      if constexpr (MODE == 0) {
        const float bv = bias[col];
#pragma unroll
        for (int i2 = 0; i2 < 4; ++i2) {
          const int row = orow + mf * 16 + i2;
          float v = fmaxf(acc[mf][nf][i2] + bv, 0.f);
          const size_t idx = (size_t)row * NCOLS + col;
          u16 h = bf16_rne(v);
          outH[idx] = h;
          outL[idx] = bf16_rne(v - bf16_to_f(h));
        }
      } else {
        float* pp = parts + (size_t)bz * Mrows * NCOLS;
#pragma unroll
        for (int i2 = 0; i2 < 4; ++i2) {
          const int row = orow + mf * 16 + i2;
          pp[(size_t)row * NCOLS + col] = acc[mf][nf][i2];
        }
      }
    }
#undef LDS8
}

// ---------------------------------------------------------------------------
// Final prev-only combine (fused path, hop HOPS-1): prev = v*uw + prev*(1-uw)
// ---------------------------------------------------------------------------
__global__ __launch_bounds__(256)
void combineF(const float* __restrict__ parts, long pstride,
              const float* __restrict__ b2, const float* __restrict__ uwp,
              float* __restrict__ prev, int n4, const int* __restrict__ gateChk) {
  if (!gchk(gateChk)) return;
  for (int idx = blockIdx.x * blockDim.x + threadIdx.x; idx < n4;
       idx += gridDim.x * blockDim.x) {
    const int row = idx >> 8, c4 = idx & 255;
    f32x4 a = ((const f32x4*)parts)[idx];
    f32x4 b = *(const f32x4*)(parts + pstride + (long)idx * 4);
    f32x4 bv = ((const f32x4*)b2)[c4];
    const float u = uwp[row];
    f32x4 pr = ((const f32x4*)prev)[idx];
    f32x4 o;
#pragma unroll
    for (int j = 0; j < 4; ++j) o[j] = (a[j] + b[j] + bv[j]) * u + pr[j] * (1.0f - u);
    ((f32x4*)prev)[idx] = o;
  }
}

// ---------------------------------------------------------------------------
// Fallback combine (sliced path): v = sum parts + b2; prev blend; state = v
// ---------------------------------------------------------------------------
__global__ __launch_bounds__(256)
void combine(const float* __restrict__ parts, long pstride, int nparts,
             const float* __restrict__ b2, const float* __restrict__ uwp,
             float* __restrict__ prev, float* __restrict__ state, int n4,
             const int* __restrict__ gateChk) {
  if (!gchk(gateChk)) return;
  for (int idx = blockIdx.x * blockDim.x + threadIdx.x; idx < n4;
       idx += gridDim.x * blockDim.x) {
    const int row = idx >> 8, c4 = idx & 255;
    f32x4 a = ((const f32x4*)parts)[idx];
    for (int k = 1; k < nparts; ++k) {
      f32x4 b = *(const f32x4*)(parts + (long)k * pstride + (long)idx * 4);
#pragma unroll
      for (int j = 0; j < 4; ++j) a[j] += b[j];
    }
    f32x4 bv = ((const f32x4*)b2)[c4];
    const float u = uwp[row];
    f32x4 pr = ((const f32x4*)prev)[idx];
    f32x4 s, o;
#pragma unroll
    for (int j = 0; j < 4; ++j) {
      s[j] = a[j] + bv[j];
      o[j] = s[j] * u + pr[j] * (1.0f - u);
    }
    ((f32x4*)prev)[idx] = o;
    ((f32x4*)state)[idx] = s;
  }
}

// ---------------------------------------------------------------------------
extern "C" void kernel_launch(void* const* d_in, const int* in_sizes, int n_in,
                              void* d_out, int out_size, void* d_ws, size_t ws_size,
                              hipStream_t stream) {
  (void)in_sizes; (void)n_in;
  float* state     = (float*)d_in[0];
  const float* ts  = (const float*)d_in[1];
  const float* ps  = (const float*)d_in[2];
  const float* wp  = (const float*)d_in[3];
  const float* bp  = (const float*)d_in[4];
  const float* W1  = (const float*)d_in[5];
  const float* b1  = (const float*)d_in[6];
  const float* W2  = (const float*)d_in[7];
  const float* b2  = (const float*)d_in[8];

  float* prev = (float*)d_out;
  float* rem  = prev + (size_t)MROWS * DIM;
  float* nu   = rem + MROWS;

  char* base = (char*)d_ws;
  size_t off = 0;
  auto carve = [&](size_t bytes) -> void* {
    void* p = base + off;
    off += (bytes + 255) & ~(size_t)255;
    return p;
  };
  u16* w1h = (u16*)carve((size_t)DFF * DIM * 2);
  u16* w1l = (u16*)carve((size_t)DFF * DIM * 2);
  u16* w2h = (u16*)carve((size_t)DIM * DFF * 2);
  u16* w2l = (u16*)carve((size_t)DIM * DFF * 2);
  u16* sh  = (u16*)carve((size_t)MROWS * DIM * 2);
  u16* sl  = (u16*)carve((size_t)MROWS * DIM * 2);
  float* uwp = (float*)carve((size_t)MROWS * 4);
  float* hp  = (float*)carve((size_t)MROWS * 4);
  int* gate  = (int*)carve(256);  // adjacent to hp: one memset covers both
  const size_t fixed = off;
  int Ms = MROWS;
  while (Ms > 256 && fixed + (size_t)16384 * DIM * 4 + (size_t)Ms * 16384 > ws_size)
    Ms >>= 1;
  u16* hidh    = (u16*)carve((size_t)Ms * DFF * 2);
  u16* hidl    = (u16*)carve((size_t)Ms * DFF * 2);
  float* parts = (float*)carve((size_t)16384 * DIM * 4);
  const int sk = 16384 / Ms;
  const int ntps = 192 / sk;
  const bool fused = (Ms == MROWS);

  hipMemsetAsync(d_out, 0, (size_t)out_size * 4, stream);
  hipMemsetAsync(hp, 0, (size_t)MROWS * 4 + 256, stream);  // hp + gate

  tsplit<<<dim3(DFF / 32, DIM / 32), 256, 0, stream>>>(W1, w1h, w1l, DIM, DFF);
  tsplit<<<dim3(DIM / 32, DFF / 32), 256, 0, stream>>>(W2, w2h, w2l, DFF, DIM);

  for (int step = 0; step < HOPS; ++step) {
    const int* gPrev = step ? &gate[step - 1] : nullptr;
    if (fused) {
      if (step == 0)
        s_act_k<0><<<MROWS, 256, 0, stream>>>(
            state, 0, nullptr, nullptr, ts, ps + (size_t)step * DIM, wp, bp,
            sh, sl, uwp, hp, rem, nu, gate, step, nullptr);
      else
        s_act_k<2><<<MROWS, 256, 0, stream>>>(
            parts, (long)MROWS * DIM, b2, prev, ts, ps + (size_t)step * DIM, wp, bp,
            sh, sl, uwp, hp, rem, nu, gate, step, gPrev);
      gemm8<0, DFF><<<dim3(DFF / 256, MROWS / 256, 1), 512, 0, stream>>>(
          sh, sl, w1h, w1l, DIM, 48, b1, hidh, hidl, nullptr, MROWS, &gate[step]);
      gemm8<1, DIM><<<dim3(DIM / 256, MROWS / 256, 2), 512, 0, stream>>>(
          hidh, hidl, w2h, w2l, DFF, 96, nullptr, nullptr, nullptr, parts, MROWS,
          &gate[step]);
    } else {
      s_act_k<0><<<MROWS, 256, 0, stream>>>(
          state, 0, nullptr, nullptr, ts, ps + (size_t)step * DIM, wp, bp,
          sh, sl, uwp, hp, rem, nu, gate, step, gPrev);
      for (int r0 = 0; r0 < MROWS; r0 += Ms) {
        gemm8<0, DFF><<<dim3(DFF / 256, Ms / 256, 1), 512, 0, stream>>>(
            sh + (size_t)r0 * DIM, sl + (size_t)r0 * DIM, w1h, w1l,
            DIM, 48, b1, hidh, hidl, nullptr, Ms, &gate[step]);
        gemm8<1, DIM><<<dim3(DIM / 256, Ms / 256, sk), 512, 0, stream>>>(
            hidh, hidl, w2h, w2l, DFF, ntps, nullptr, nullptr, nullptr, parts, Ms,
            &gate[step]);
        combine<<<2048, 256, 0, stream>>>(
            parts, (long)Ms * DIM, sk, b2, uwp + r0,
            prev + (size_t)r0 * DIM, state + (size_t)r0 * DIM, Ms * 256, &gate[step]);
      }
    }
  }
  if (fused)
    combineF<<<2048, 256, 0, stream>>>(parts, (long)MROWS * DIM, b2, uwp, prev,
                                       MROWS * 256, &gate[HOPS - 1]);
}